// Round 1
// baseline (670.820 us; speedup 1.0000x reference)
//
#include <hip/hip_runtime.h>
#include <stdint.h>

#define NB 32768

typedef __bf16 bf16x8 __attribute__((ext_vector_type(8)));
typedef float f32x4 __attribute__((ext_vector_type(4)));

__device__ __forceinline__ unsigned short f2bf(float f) {
  union { float f; unsigned u; } v; v.f = f;
  unsigned r = v.u + 0x7fffu + ((v.u >> 16) & 1u);
  return (unsigned short)(r >> 16);
}
__device__ __forceinline__ float bf2f(unsigned short h) {
  union { unsigned u; float f; } v; v.u = ((unsigned)h) << 16;
  return v.f;
}

// global -> LDS direct copy, 16B per lane. LDS dest is wave-uniform base + lane*16.
__device__ __forceinline__ void gld_lds16(void* lds, const void* g) {
  __builtin_amdgcn_global_load_lds(
      (__attribute__((address_space(1))) unsigned int*)(uintptr_t)g,
      (__attribute__((address_space(3))) unsigned int*)(uintptr_t)lds,
      16, 0, 0);
}

// ---------------- prep kernels ----------------

__global__ __launch_bounds__(256) void fconv_k(const float* __restrict__ src,
                                               unsigned short* __restrict__ dst) {
  size_t idx = ((size_t)blockIdx.x * 256 + threadIdx.x) * 8;
  float4 a = *(const float4*)(src + idx);
  float4 b = *(const float4*)(src + idx + 4);
  union { unsigned short us[8]; uint4 v; } u;
  u.us[0] = f2bf(a.x); u.us[1] = f2bf(a.y); u.us[2] = f2bf(a.z); u.us[3] = f2bf(a.w);
  u.us[4] = f2bf(b.x); u.us[5] = f2bf(b.y); u.us[6] = f2bf(b.z); u.us[7] = f2bf(b.w);
  *(uint4*)(dst + idx) = u.v;
}

struct TJobs {
  const float* src[11];
  unsigned short* dst[11];
  int K[11], N[11], batch[11];
};

// transpose fp32 [K][N] -> bf16 [N][K], batched, 32x32 tiles
__global__ __launch_bounds__(256) void wtrans_k(TJobs jobs) {
  const int job = blockIdx.y;
  const int K = jobs.K[job], N = jobs.N[job];
  const int KT = K >> 5, NT = N >> 5;
  const int ntiles = jobs.batch[job] * KT * NT;
  const int t = blockIdx.x;
  if (t >= ntiles) return;
  const int b = t / (KT * NT);
  const int rem = t - b * KT * NT;
  const int kt = rem / NT, nt = rem - kt * NT;
  const float* src = jobs.src[job] + (size_t)b * K * N;
  unsigned short* dst = jobs.dst[job] + (size_t)b * K * N;
  __shared__ float tile[32][33];
  const int i = threadIdx.x >> 5, jj = threadIdx.x & 31;
#pragma unroll
  for (int s = 0; s < 4; ++s)
    tile[i + 8 * s][jj] = src[(size_t)(kt * 32 + i + 8 * s) * N + nt * 32 + jj];
  __syncthreads();
#pragma unroll
  for (int s = 0; s < 4; ++s)
    dst[(size_t)(nt * 32 + i + 8 * s) * K + kt * 32 + jj] = f2bf(tile[jj][i + 8 * s]);
}

// ---------------- main GEMM: C = relu(A @ W + b), A bf16 [M][lda], WT bf16 [N][K] ----------------
// 128x128 tile, 4 waves (2x2), each wave 64x64 = 4x4 frags of 16x16x32.

template <bool OUT_BF16>
__global__ __launch_bounds__(256) void gemm_k(const unsigned short* __restrict__ A, int lda,
                                              const unsigned short* __restrict__ WT,
                                              const float* __restrict__ bias,
                                              void* __restrict__ Cout, int ldc, int K) {
  __shared__ unsigned short lds_a[128 * 32];
  __shared__ unsigned short lds_b[128 * 32];
  const int tid = threadIdx.x;
  const int l = tid & 63, w = tid >> 6;
  const int wm = w >> 1, wn = w & 1;
  const int lr = l & 15, lq = l >> 4;
  const int row0 = blockIdx.x << 7;
  const int col0 = blockIdx.y << 7;
  const int srow = tid >> 2;  // 0..63
  const int scg = tid & 3;
  const int wbase = tid & ~63;

  f32x4 acc[4][4] = {};

  for (int k0 = 0; k0 < K; k0 += 32) {
#pragma unroll
    for (int i = 0; i < 2; ++i) {
      const int r = i * 64 + srow;
      gld_lds16(&lds_a[(size_t)(i * 256 + wbase) * 8],
                A + (size_t)(row0 + r) * lda + k0 + scg * 8);
      gld_lds16(&lds_b[(size_t)(i * 256 + wbase) * 8],
                WT + (size_t)(col0 + r) * K + k0 + scg * 8);
    }
    __syncthreads();
    bf16x8 av[4], bv[4];
#pragma unroll
    for (int mf = 0; mf < 4; ++mf)
      av[mf] = *(const bf16x8*)&lds_a[((wm * 64 + mf * 16 + lr) << 5) + (lq << 3)];
#pragma unroll
    for (int nf = 0; nf < 4; ++nf)
      bv[nf] = *(const bf16x8*)&lds_b[((wn * 64 + nf * 16 + lr) << 5) + (lq << 3)];
#pragma unroll
    for (int mf = 0; mf < 4; ++mf)
#pragma unroll
      for (int nf = 0; nf < 4; ++nf)
        acc[mf][nf] = __builtin_amdgcn_mfma_f32_16x16x32_bf16(av[mf], bv[nf], acc[mf][nf], 0, 0, 0);
    __syncthreads();
  }

#pragma unroll
  for (int nf = 0; nf < 4; ++nf) {
    const int gc = col0 + wn * 64 + nf * 16 + lr;
    const float bb = bias[gc];
#pragma unroll
    for (int mf = 0; mf < 4; ++mf) {
      const int gr = row0 + wm * 64 + mf * 16 + (lq << 2);
#pragma unroll
      for (int r = 0; r < 4; ++r) {
        float v = acc[mf][nf][r] + bb;
        v = fmaxf(v, 0.0f);
        if (OUT_BF16)
          ((unsigned short*)Cout)[(size_t)(gr + r) * ldc + gc] = f2bf(v);
        else
          ((float*)Cout)[(size_t)(gr + r) * ldc + gc] = v;
      }
    }
  }
}

// ---------------- gate head 2: weights = sigmoid(gate_h @ gt_w2 + gt_b2), N=16 ----------------

__global__ __launch_bounds__(256) void gt2_k(const unsigned short* __restrict__ gate_h,
                                             const float* __restrict__ w2,
                                             const float* __restrict__ b2,
                                             float* __restrict__ wgt) {
  __shared__ float w_s[256 * 16];
  __shared__ unsigned short a_s[16 * 264];
  const int tid = threadIdx.x;
  const int row0 = blockIdx.x * 16;
  for (int i = tid; i < 256 * 16; i += 256) w_s[i] = w2[i];
  for (int i = tid; i < 512; i += 256) {
    const int r = i >> 5, cg = i & 31;
    *(uint4*)&a_s[r * 264 + cg * 8] =
        *(const uint4*)(gate_h + (size_t)(row0 + r) * 256 + cg * 8);
  }
  __syncthreads();
  const int rr = tid >> 4, col = tid & 15;
  float sum = b2[col];
#pragma unroll 8
  for (int k = 0; k < 256; ++k)
    sum += bf2f(a_s[rr * 264 + k]) * w_s[k * 16 + col];
  wgt[(size_t)(row0 + rr) * 16 + col] = 1.0f / (1.0f + __expf(-sum));
}

// ---------------- fused primitive mixture ----------------
// per block: 64 rows, 8 waves (2 row-blocks x 4 col-blocks).
// p-loop: h = relu(prim @ pw1[p] + pb1[p]) (64x256, h in LDS),
//         out = h @ pw2[p] + pb2[p] (64x64), then online mixture accumulation.
// pw1t/pw2t fragments are read directly from global (L2-resident, 2.5MB).

__global__ __launch_bounds__(512) void mixture_k(const unsigned short* __restrict__ prim,
                                                 const float* __restrict__ wgt,
                                                 const unsigned short* __restrict__ pw1t,
                                                 const float* __restrict__ pb1,
                                                 const unsigned short* __restrict__ pw2t,
                                                 const float* __restrict__ pb2,
                                                 float* __restrict__ mean_out) {
  __shared__ unsigned short prim_s[32 * 64 * 8];  // [kq][row][8]
  __shared__ unsigned short h_s[32 * 64 * 8];     // [nq][row][8]
  __shared__ float out_s[64 * 64];
  __shared__ float wgt_s[64 * 16];
  const int tid = threadIdx.x;
  const int l = tid & 63, w = tid >> 6;
  const int lr = l & 15, lq = l >> 4;
  const int wm = w >> 2, wn = w & 3;
  const int row0 = blockIdx.x << 6;
  const int wbase = tid & ~63;

#pragma unroll
  for (int i = 0; i < 4; ++i) {
    const int c = i * 512 + tid;
    const int kq = c >> 6, rw = c & 63;
    gld_lds16(&prim_s[(size_t)(i * 512 + wbase) * 8],
              prim + (size_t)(row0 + rw) * 256 + kq * 8);
  }
  if (tid < 256)
    ((float4*)wgt_s)[tid] = ((const float4*)(wgt + (size_t)row0 * 16))[tid];
  __syncthreads();

  float num[4] = {0, 0, 0, 0}, den[4] = {0, 0, 0, 0};
  const int mrow = tid >> 3;
  const int ma0 = (tid & 7) << 2;

#pragma unroll 1
  for (int p = 0; p < 16; ++p) {
    // phase 1
    f32x4 acc1[2][4] = {};
    const unsigned short* w1p = pw1t + (size_t)p * 65536;
#pragma unroll
    for (int kq8 = 0; kq8 < 8; ++kq8) {
      bf16x8 av[2];
#pragma unroll
      for (int mf = 0; mf < 2; ++mf)
        av[mf] = *(const bf16x8*)&prim_s[((kq8 * 4 + lq) * 64 + wm * 32 + mf * 16 + lr) * 8];
#pragma unroll
      for (int nf = 0; nf < 4; ++nf) {
        const bf16x8 bv =
            *(const bf16x8*)(w1p + (size_t)(wn * 64 + nf * 16 + lr) * 256 + kq8 * 32 + lq * 8);
#pragma unroll
        for (int mf = 0; mf < 2; ++mf)
          acc1[mf][nf] = __builtin_amdgcn_mfma_f32_16x16x32_bf16(av[mf], bv, acc1[mf][nf], 0, 0, 0);
      }
    }
    // write h (K-tiled layout [n>>3][row][n&7])
#pragma unroll
    for (int nf = 0; nf < 4; ++nf) {
      const int n = wn * 64 + nf * 16 + lr;
      const float bb = pb1[p * 256 + n];
#pragma unroll
      for (int mf = 0; mf < 2; ++mf) {
#pragma unroll
        for (int r = 0; r < 4; ++r) {
          const int rw = wm * 32 + mf * 16 + (lq << 2) + r;
          h_s[(size_t)((n >> 3) * 64 + rw) * 8 + (n & 7)] =
              f2bf(fmaxf(acc1[mf][nf][r] + bb, 0.0f));
        }
      }
    }
    __syncthreads();
    // phase 2
    f32x4 acc2[2] = {};
    const unsigned short* w2p = pw2t + (size_t)p * 16384;
#pragma unroll
    for (int kq8 = 0; kq8 < 8; ++kq8) {
      bf16x8 av[2];
#pragma unroll
      for (int mf = 0; mf < 2; ++mf)
        av[mf] = *(const bf16x8*)&h_s[((kq8 * 4 + lq) * 64 + wm * 32 + mf * 16 + lr) * 8];
      const bf16x8 bv =
          *(const bf16x8*)(w2p + (size_t)(wn * 16 + lr) * 256 + kq8 * 32 + lq * 8);
#pragma unroll
      for (int mf = 0; mf < 2; ++mf)
        acc2[mf] = __builtin_amdgcn_mfma_f32_16x16x32_bf16(av[mf], bv, acc2[mf], 0, 0, 0);
    }
    {
      const int d = wn * 16 + lr;
      const float bb = pb2[p * 64 + d];
#pragma unroll
      for (int mf = 0; mf < 2; ++mf)
#pragma unroll
        for (int r = 0; r < 4; ++r)
          out_s[(wm * 32 + mf * 16 + (lq << 2) + r) * 64 + d] = acc2[mf][r] + bb;
    }
    __syncthreads();
    // phase 3: online mixture accumulation
    {
      const float wp = wgt_s[mrow * 16 + p];
#pragma unroll
      for (int j = 0; j < 4; ++j) {
        const float mu = out_s[mrow * 64 + ma0 + j];
        const float ls = out_s[mrow * 64 + 32 + ma0 + j];
        const float iv = wp * __expf(-ls);
        num[j] += iv * mu;
        den[j] += iv;
      }
    }
  }
  float4 res;
  res.x = num[0] / den[0];
  res.y = num[1] / den[1];
  res.z = num[2] / den[2];
  res.w = num[3] / den[3];
  *(float4*)(mean_out + (size_t)(row0 + mrow) * 32 + ma0) = res;
}

// ---------------- launcher ----------------

extern "C" void kernel_launch(void* const* d_in, const int* in_sizes, int n_in,
                              void* d_out, int out_size, void* d_ws, size_t ws_size,
                              hipStream_t stream) {
  const float* features = (const float*)d_in[0];
  const float* se_w1 = (const float*)d_in[1];
  const float* se_b1 = (const float*)d_in[2];
  const float* se_w2 = (const float*)d_in[3];
  const float* se_b2 = (const float*)d_in[4];
  const float* ge_w1 = (const float*)d_in[5];
  const float* ge_b1 = (const float*)d_in[6];
  const float* ge_w2 = (const float*)d_in[7];
  const float* ge_b2 = (const float*)d_in[8];
  const float* gt_w1 = (const float*)d_in[9];
  const float* gt_b1 = (const float*)d_in[10];
  const float* gt_w2 = (const float*)d_in[11];
  const float* gt_b2 = (const float*)d_in[12];
  const float* pse_w1 = (const float*)d_in[13];
  const float* pse_b1 = (const float*)d_in[14];
  const float* pse_w2 = (const float*)d_in[15];
  const float* pse_b2 = (const float*)d_in[16];
  const float* pw1 = (const float*)d_in[17];
  const float* pb1 = (const float*)d_in[18];
  const float* pw2 = (const float*)d_in[19];
  const float* pb2 = (const float*)d_in[20];
  const float* vf_w1 = (const float*)d_in[21];
  const float* vf_b1 = (const float*)d_in[22];
  const float* vf_w2 = (const float*)d_in[23];
  const float* vf_b2 = (const float*)d_in[24];
  (void)in_sizes; (void)n_in; (void)out_size; (void)ws_size;

  char* base = (char*)d_ws;
  size_t off = 0;
  auto alloc = [&](size_t bytes) -> char* {
    char* p = base + off;
    off += (bytes + 255) & ~(size_t)255;
    return p;
  };
  unsigned short* fbf     = (unsigned short*)alloc((size_t)NB * 640 * 2);
  unsigned short* bufA    = (unsigned short*)alloc((size_t)NB * 1024 * 2);  // s1 / p1 / v1
  unsigned short* g1      = (unsigned short*)alloc((size_t)NB * 512 * 2);
  unsigned short* gate_in = (unsigned short*)alloc((size_t)NB * 512 * 2);
  unsigned short* gate_h  = (unsigned short*)alloc((size_t)NB * 256 * 2);
  unsigned short* prim    = (unsigned short*)alloc((size_t)NB * 256 * 2);
  float* wgt              = (float*)alloc((size_t)NB * 16 * 4);
  unsigned short* se_w1t  = (unsigned short*)alloc(512 * 512 * 2);
  unsigned short* se_w2t  = (unsigned short*)alloc(256 * 512 * 2);
  unsigned short* ge_w1t  = (unsigned short*)alloc(512 * 128 * 2);
  unsigned short* ge_w2t  = (unsigned short*)alloc(256 * 512 * 2);
  unsigned short* gt_w1t  = (unsigned short*)alloc(256 * 512 * 2);
  unsigned short* pse_w1t = (unsigned short*)alloc(512 * 512 * 2);
  unsigned short* pse_w2t = (unsigned short*)alloc(256 * 512 * 2);
  unsigned short* pw1t    = (unsigned short*)alloc((size_t)16 * 256 * 256 * 2);
  unsigned short* pw2t    = (unsigned short*)alloc((size_t)16 * 64 * 256 * 2);
  unsigned short* vf_w1t  = (unsigned short*)alloc(1024 * 640 * 2);
  unsigned short* vf_w2t  = (unsigned short*)alloc(512 * 1024 * 2);

  float* mean_out = (float*)d_out;
  float* value_out = (float*)d_out + (size_t)NB * 32;

  fconv_k<<<dim3(10240), dim3(256), 0, stream>>>(features, fbf);

  TJobs jobs;
  auto setj = [&](int i, const float* s, unsigned short* d, int K, int N, int b) {
    jobs.src[i] = s; jobs.dst[i] = d; jobs.K[i] = K; jobs.N[i] = N; jobs.batch[i] = b;
  };
  setj(0, se_w1, se_w1t, 512, 512, 1);
  setj(1, se_w2, se_w2t, 512, 256, 1);
  setj(2, ge_w1, ge_w1t, 128, 512, 1);
  setj(3, ge_w2, ge_w2t, 512, 256, 1);
  setj(4, gt_w1, gt_w1t, 512, 256, 1);
  setj(5, pse_w1, pse_w1t, 512, 512, 1);
  setj(6, pse_w2, pse_w2t, 512, 256, 1);
  setj(7, pw1, pw1t, 256, 256, 16);
  setj(8, pw2, pw2t, 256, 64, 16);
  setj(9, vf_w1, vf_w1t, 640, 1024, 1);
  setj(10, vf_w2, vf_w2t, 1024, 512, 1);
  wtrans_k<<<dim3(1024, 11), dim3(256), 0, stream>>>(jobs);

  // s1 = relu(state @ se_w1 + b)
  gemm_k<true><<<dim3(256, 4), dim3(256), 0, stream>>>(fbf, 640, se_w1t, se_b1, bufA, 512, 512);
  // gate_in[:, :256] = relu(s1 @ se_w2 + b)
  gemm_k<true><<<dim3(256, 2), dim3(256), 0, stream>>>(bufA, 512, se_w2t, se_b2, gate_in, 512, 512);
  // g1 = relu(goal @ ge_w1 + b)
  gemm_k<true><<<dim3(256, 4), dim3(256), 0, stream>>>(fbf + 512, 640, ge_w1t, ge_b1, g1, 512, 128);
  // gate_in[:, 256:] = relu(g1 @ ge_w2 + b)
  gemm_k<true><<<dim3(256, 2), dim3(256), 0, stream>>>(g1, 512, ge_w2t, ge_b2, gate_in + 256, 512, 512);
  // gate_h = relu(gate_in @ gt_w1 + b)
  gemm_k<true><<<dim3(256, 2), dim3(256), 0, stream>>>(gate_in, 512, gt_w1t, gt_b1, gate_h, 256, 512);
  // weights = sigmoid(gate_h @ gt_w2 + b)
  gt2_k<<<dim3(2048), dim3(256), 0, stream>>>(gate_h, gt_w2, gt_b2, wgt);
  // p1 = relu(state @ pse_w1 + b)
  gemm_k<true><<<dim3(256, 4), dim3(256), 0, stream>>>(fbf, 640, pse_w1t, pse_b1, bufA, 512, 512);
  // prim = relu(p1 @ pse_w2 + b)
  gemm_k<true><<<dim3(256, 2), dim3(256), 0, stream>>>(bufA, 512, pse_w2t, pse_b2, prim, 256, 512);
  // mean head (fused einsums + mixture)
  mixture_k<<<dim3(512), dim3(512), 0, stream>>>(prim, wgt, pw1t, pb1, pw2t, pb2, mean_out);
  // v1 = relu(features @ vf_w1 + b)
  gemm_k<true><<<dim3(256, 8), dim3(256), 0, stream>>>(fbf, 640, vf_w1t, vf_b1, bufA, 1024, 640);
  // value = relu(v1 @ vf_w2 + b)  (fp32 out)
  gemm_k<false><<<dim3(256, 4), dim3(256), 0, stream>>>(bufA, 1024, vf_w2t, vf_b2, value_out, 512, 1024);
}

// Round 2
// 634.947 us; speedup vs baseline: 1.0565x; 1.0565x over previous
//
#include <hip/hip_runtime.h>
#include <stdint.h>

#define NB 32768

typedef __bf16 bf16x8 __attribute__((ext_vector_type(8)));
typedef float f32x4 __attribute__((ext_vector_type(4)));

__device__ __forceinline__ unsigned short f2bf(float f) {
  union { float f; unsigned u; } v; v.f = f;
  unsigned r = v.u + 0x7fffu + ((v.u >> 16) & 1u);
  return (unsigned short)(r >> 16);
}
__device__ __forceinline__ float bf2f(unsigned short h) {
  union { unsigned u; float f; } v; v.u = ((unsigned)h) << 16;
  return v.f;
}

// global -> LDS direct copy, 16B per lane. LDS dest is wave-uniform base + lane*16.
__device__ __forceinline__ void gld_lds16(void* lds, const void* g) {
  __builtin_amdgcn_global_load_lds(
      (__attribute__((address_space(1))) unsigned int*)(uintptr_t)g,
      (__attribute__((address_space(3))) unsigned int*)(uintptr_t)lds,
      16, 0, 0);
}

// ---------------- prep kernels ----------------

__global__ __launch_bounds__(256) void fconv_k(const float* __restrict__ src,
                                               unsigned short* __restrict__ dst) {
  size_t idx = ((size_t)blockIdx.x * 256 + threadIdx.x) * 8;
  float4 a = *(const float4*)(src + idx);
  float4 b = *(const float4*)(src + idx + 4);
  union { unsigned short us[8]; uint4 v; } u;
  u.us[0] = f2bf(a.x); u.us[1] = f2bf(a.y); u.us[2] = f2bf(a.z); u.us[3] = f2bf(a.w);
  u.us[4] = f2bf(b.x); u.us[5] = f2bf(b.y); u.us[6] = f2bf(b.z); u.us[7] = f2bf(b.w);
  *(uint4*)(dst + idx) = u.v;
}

struct TJobs {
  const float* src[11];
  unsigned short* dst[11];
  int K[11], N[11], batch[11];
};

// transpose fp32 [K][N] -> bf16 [N][K], batched, 32x32 tiles
__global__ __launch_bounds__(256) void wtrans_k(TJobs jobs) {
  const int job = blockIdx.y;
  const int K = jobs.K[job], N = jobs.N[job];
  const int KT = K >> 5, NT = N >> 5;
  const int ntiles = jobs.batch[job] * KT * NT;
  const int t = blockIdx.x;
  if (t >= ntiles) return;
  const int b = t / (KT * NT);
  const int rem = t - b * KT * NT;
  const int kt = rem / NT, nt = rem - kt * NT;
  const float* src = jobs.src[job] + (size_t)b * K * N;
  unsigned short* dst = jobs.dst[job] + (size_t)b * K * N;
  __shared__ float tile[32][33];
  const int i = threadIdx.x >> 5, jj = threadIdx.x & 31;
#pragma unroll
  for (int s = 0; s < 4; ++s)
    tile[i + 8 * s][jj] = src[(size_t)(kt * 32 + i + 8 * s) * N + nt * 32 + jj];
  __syncthreads();
#pragma unroll
  for (int s = 0; s < 4; ++s)
    dst[(size_t)(nt * 32 + i + 8 * s) * K + kt * 32 + jj] = f2bf(tile[jj][i + 8 * s]);
}

// ---------------- main GEMM: C = relu(A @ W + b), A bf16 [M][lda], WT bf16 [N][K] ----------------
// 128x128 tile, 4 waves (2x2), each wave 64x64 = 4x4 frags of 16x16x32.

template <bool OUT_BF16>
__global__ __launch_bounds__(256) void gemm_k(const unsigned short* __restrict__ A, int lda,
                                              const unsigned short* __restrict__ WT,
                                              const float* __restrict__ bias,
                                              void* __restrict__ Cout, int ldc, int K) {
  __shared__ unsigned short lds_a[128 * 32];
  __shared__ unsigned short lds_b[128 * 32];
  const int tid = threadIdx.x;
  const int l = tid & 63, w = tid >> 6;
  const int wm = w >> 1, wn = w & 1;
  const int lr = l & 15, lq = l >> 4;
  const int row0 = blockIdx.x << 7;
  const int col0 = blockIdx.y << 7;
  const int srow = tid >> 2;  // 0..63
  const int scg = tid & 3;
  const int wbase = tid & ~63;

  f32x4 acc[4][4] = {};

  for (int k0 = 0; k0 < K; k0 += 32) {
#pragma unroll
    for (int i = 0; i < 2; ++i) {
      const int r = i * 64 + srow;
      gld_lds16(&lds_a[(size_t)(i * 256 + wbase) * 8],
                A + (size_t)(row0 + r) * lda + k0 + scg * 8);
      gld_lds16(&lds_b[(size_t)(i * 256 + wbase) * 8],
                WT + (size_t)(col0 + r) * K + k0 + scg * 8);
    }
    __syncthreads();
    bf16x8 av[4], bv[4];
#pragma unroll
    for (int mf = 0; mf < 4; ++mf)
      av[mf] = *(const bf16x8*)&lds_a[((wm * 64 + mf * 16 + lr) << 5) + (lq << 3)];
#pragma unroll
    for (int nf = 0; nf < 4; ++nf)
      bv[nf] = *(const bf16x8*)&lds_b[((wn * 64 + nf * 16 + lr) << 5) + (lq << 3)];
#pragma unroll
    for (int mf = 0; mf < 4; ++mf)
#pragma unroll
      for (int nf = 0; nf < 4; ++nf)
        acc[mf][nf] = __builtin_amdgcn_mfma_f32_16x16x32_bf16(av[mf], bv[nf], acc[mf][nf], 0, 0, 0);
    __syncthreads();
  }

#pragma unroll
  for (int nf = 0; nf < 4; ++nf) {
    const int gc = col0 + wn * 64 + nf * 16 + lr;
    const float bb = bias[gc];
#pragma unroll
    for (int mf = 0; mf < 4; ++mf) {
      const int gr = row0 + wm * 64 + mf * 16 + (lq << 2);
#pragma unroll
      for (int r = 0; r < 4; ++r) {
        float v = acc[mf][nf][r] + bb;
        v = fmaxf(v, 0.0f);
        if (OUT_BF16)
          ((unsigned short*)Cout)[(size_t)(gr + r) * ldc + gc] = f2bf(v);
        else
          ((float*)Cout)[(size_t)(gr + r) * ldc + gc] = v;
      }
    }
  }
}

// ---------------- gate head 2: weights = sigmoid(gate_h @ gt_w2 + gt_b2), N=16 ----------------

__global__ __launch_bounds__(256) void gt2_k(const unsigned short* __restrict__ gate_h,
                                             const float* __restrict__ w2,
                                             const float* __restrict__ b2,
                                             float* __restrict__ wgt) {
  __shared__ float w_s[256 * 16];
  __shared__ unsigned short a_s[16 * 264];
  const int tid = threadIdx.x;
  const int row0 = blockIdx.x * 16;
  for (int i = tid; i < 256 * 16; i += 256) w_s[i] = w2[i];
  for (int i = tid; i < 512; i += 256) {
    const int r = i >> 5, cg = i & 31;
    *(uint4*)&a_s[r * 264 + cg * 8] =
        *(const uint4*)(gate_h + (size_t)(row0 + r) * 256 + cg * 8);
  }
  __syncthreads();
  const int rr = tid >> 4, col = tid & 15;
  float sum = b2[col];
#pragma unroll 8
  for (int k = 0; k < 256; ++k)
    sum += bf2f(a_s[rr * 264 + k]) * w_s[k * 16 + col];
  wgt[(size_t)(row0 + rr) * 16 + col] = 1.0f / (1.0f + __expf(-sum));
}

// ---------------- primitive head: per (row-tile, p) block ----------------
// block = 128 rows x one p, 8 waves (2 wm x 4 wn).
// phase 1: h[128][256] = relu(prim_tile @ pw1[p] + pb1[p])  (h in LDS, K-tiled)
// phase 2: out[128][64] = h @ pw2[p] + pb2[p]               (pw2[p] LDS-staged)
// epilogue: iv = wgt[row][p]*exp(-ls); write ivmu & iv fp32 to outbuf[row][p][64].

__global__ __launch_bounds__(512) void prim_head_k(
    const unsigned short* __restrict__ prim,   // [B][256] bf16
    const float* __restrict__ wgt,             // [B][16]
    const unsigned short* __restrict__ pw1t,   // [16][256n][256k] bf16
    const float* __restrict__ pb1,             // [16][256]
    const unsigned short* __restrict__ pw2t,   // [16][64n][256k] bf16
    const float* __restrict__ pb2,             // [16][64]
    float* __restrict__ outbuf)                // [B][16][64] fp32
{
  __shared__ unsigned short prim_s[4 * 128 * 8];   // 8KB  [kq4][row128][8]
  __shared__ unsigned short w1_s[4 * 256 * 8];     // 16KB [kq4][n256][8]
  __shared__ unsigned short h_s[32 * 128 * 8];     // 64KB [nq32][row128][8]
  __shared__ unsigned short pw2_s[32 * 64 * 8];    // 32KB [kq32][n64][8]
  __shared__ float out_s[128 * 64];                // 32KB
  const int tid = threadIdx.x;
  const int l = tid & 63;
  const int w = tid >> 6;
  const int lr = l & 15, lq = l >> 4;
  const int wm = w >> 2, wn = w & 3;   // wm 0..1, wn 0..3
  const int row0 = blockIdx.x << 7;
  const int p = blockIdx.y;
  const int wbase = tid & ~63;

  const unsigned short* w1p = pw1t + (size_t)p * 65536;
  const unsigned short* w2p = pw2t + (size_t)p * 16384;

  // stage pw2[p] (32KB): 2048 chunks of 16B, 4 per thread
#pragma unroll
  for (int i = 0; i < 4; ++i) {
    const int c = i * 512 + tid;
    const int kq = c >> 6, n = c & 63;
    gld_lds16(&pw2_s[(size_t)(i * 512 + wbase) * 8], w2p + (size_t)n * 256 + kq * 8);
  }

  // ---- phase 1: h = relu(prim @ pw1[p] + pb1[p]) ----
  f32x4 acc[4][4] = {};
  for (int ks = 0; ks < 8; ++ks) {
    const int k0 = ks * 32;
    {  // prim tile [kq4][row128][8]: 512 chunks, 1/thread
      const int rw = tid & 127, kq = tid >> 7;
      gld_lds16(&prim_s[(size_t)wbase * 8], prim + (size_t)(row0 + rw) * 256 + k0 + kq * 8);
    }
#pragma unroll
    for (int i = 0; i < 2; ++i) {  // w1 tile [kq4][n256][8]: 1024 chunks, 2/thread
      const int c = i * 512 + tid;
      const int kq = c >> 8, n = c & 255;
      gld_lds16(&w1_s[(size_t)(i * 512 + wbase) * 8], w1p + (size_t)n * 256 + k0 + kq * 8);
    }
    __syncthreads();
    bf16x8 av[4], bv[4];
#pragma unroll
    for (int mf = 0; mf < 4; ++mf)
      av[mf] = *(const bf16x8*)&prim_s[((size_t)lq * 128 + wm * 64 + mf * 16 + lr) * 8];
#pragma unroll
    for (int nf = 0; nf < 4; ++nf)
      bv[nf] = *(const bf16x8*)&w1_s[((size_t)lq * 256 + wn * 64 + nf * 16 + lr) * 8];
#pragma unroll
    for (int mf = 0; mf < 4; ++mf)
#pragma unroll
      for (int nf = 0; nf < 4; ++nf)
        acc[mf][nf] = __builtin_amdgcn_mfma_f32_16x16x32_bf16(av[mf], bv[nf], acc[mf][nf], 0, 0, 0);
    __syncthreads();
  }

  // write h (K-tiled layout [n>>3][row][n&7])
#pragma unroll
  for (int nf = 0; nf < 4; ++nf) {
    const int n = wn * 64 + nf * 16 + lr;
    const float bb = pb1[p * 256 + n];
#pragma unroll
    for (int mf = 0; mf < 4; ++mf) {
#pragma unroll
      for (int r = 0; r < 4; ++r) {
        const int rw = wm * 64 + mf * 16 + (lq << 2) + r;
        h_s[(size_t)((n >> 3) * 128 + rw) * 8 + (n & 7)] = f2bf(fmaxf(acc[mf][nf][r] + bb, 0.0f));
      }
    }
  }
  __syncthreads();

  // ---- phase 2: out = h @ pw2[p] + pb2[p] ----
  f32x4 acc2[4] = {};
#pragma unroll
  for (int kc = 0; kc < 8; ++kc) {
    const bf16x8 bv2 = *(const bf16x8*)&pw2_s[((size_t)(kc * 4 + lq) * 64 + wn * 16 + lr) * 8];
#pragma unroll
    for (int mf = 0; mf < 4; ++mf) {
      const bf16x8 av2 =
          *(const bf16x8*)&h_s[((size_t)(kc * 4 + lq) * 128 + wm * 64 + mf * 16 + lr) * 8];
      acc2[mf] = __builtin_amdgcn_mfma_f32_16x16x32_bf16(av2, bv2, acc2[mf], 0, 0, 0);
    }
  }
  {
    const int d = wn * 16 + lr;
    const float bb = pb2[p * 64 + d];
#pragma unroll
    for (int mf = 0; mf < 4; ++mf)
#pragma unroll
      for (int r = 0; r < 4; ++r)
        out_s[(size_t)(wm * 64 + mf * 16 + (lq << 2) + r) * 64 + d] = acc2[mf][r] + bb;
  }
  __syncthreads();

  // ---- epilogue: iv = wgt*exp(-ls); write ivmu, iv ----
  {
    const int frow = tid >> 2;          // 0..127
    const int a0 = (tid & 3) * 8;       // 0,8,16,24
    const float wp = wgt[(size_t)(row0 + frow) * 16 + p];
    float* ob = outbuf + ((size_t)(row0 + frow) * 16 + p) * 64;
    float4 mu0 = *(float4*)&out_s[frow * 64 + a0];
    float4 mu1 = *(float4*)&out_s[frow * 64 + a0 + 4];
    float4 ls0 = *(float4*)&out_s[frow * 64 + 32 + a0];
    float4 ls1 = *(float4*)&out_s[frow * 64 + 32 + a0 + 4];
    float4 iv0, iv1, nm0, nm1;
    iv0.x = wp * __expf(-ls0.x); iv0.y = wp * __expf(-ls0.y);
    iv0.z = wp * __expf(-ls0.z); iv0.w = wp * __expf(-ls0.w);
    iv1.x = wp * __expf(-ls1.x); iv1.y = wp * __expf(-ls1.y);
    iv1.z = wp * __expf(-ls1.z); iv1.w = wp * __expf(-ls1.w);
    nm0.x = iv0.x * mu0.x; nm0.y = iv0.y * mu0.y; nm0.z = iv0.z * mu0.z; nm0.w = iv0.w * mu0.w;
    nm1.x = iv1.x * mu1.x; nm1.y = iv1.y * mu1.y; nm1.z = iv1.z * mu1.z; nm1.w = iv1.w * mu1.w;
    *(float4*)(ob + a0) = nm0;
    *(float4*)(ob + a0 + 4) = nm1;
    *(float4*)(ob + 32 + a0) = iv0;
    *(float4*)(ob + 32 + a0 + 4) = iv1;
  }
}

// ---------------- mixture finish: mean = sum_p ivmu / sum_p iv ----------------

__global__ __launch_bounds__(256) void mix_finish_k(const float* __restrict__ buf,  // [B][16][64]
                                                    float* __restrict__ mean_out) { // [B][32]
  const int gid = blockIdx.x * 256 + threadIdx.x;
  const int row = gid >> 3;
  const int a0 = (gid & 7) * 4;
  const float* rp = buf + (size_t)row * 1024;
  float nx = 0, ny = 0, nz = 0, nw = 0, dx = 0, dy = 0, dz = 0, dw = 0;
#pragma unroll
  for (int p = 0; p < 16; ++p) {
    float4 m = *(const float4*)(rp + p * 64 + a0);
    float4 v = *(const float4*)(rp + p * 64 + 32 + a0);
    nx += m.x; ny += m.y; nz += m.z; nw += m.w;
    dx += v.x; dy += v.y; dz += v.z; dw += v.w;
  }
  float4 res;
  res.x = nx / dx; res.y = ny / dy; res.z = nz / dz; res.w = nw / dw;
  *(float4*)(mean_out + (size_t)row * 32 + a0) = res;
}

// ---------------- launcher ----------------

extern "C" void kernel_launch(void* const* d_in, const int* in_sizes, int n_in,
                              void* d_out, int out_size, void* d_ws, size_t ws_size,
                              hipStream_t stream) {
  const float* features = (const float*)d_in[0];
  const float* se_w1 = (const float*)d_in[1];
  const float* se_b1 = (const float*)d_in[2];
  const float* se_w2 = (const float*)d_in[3];
  const float* se_b2 = (const float*)d_in[4];
  const float* ge_w1 = (const float*)d_in[5];
  const float* ge_b1 = (const float*)d_in[6];
  const float* ge_w2 = (const float*)d_in[7];
  const float* ge_b2 = (const float*)d_in[8];
  const float* gt_w1 = (const float*)d_in[9];
  const float* gt_b1 = (const float*)d_in[10];
  const float* gt_w2 = (const float*)d_in[11];
  const float* gt_b2 = (const float*)d_in[12];
  const float* pse_w1 = (const float*)d_in[13];
  const float* pse_b1 = (const float*)d_in[14];
  const float* pse_w2 = (const float*)d_in[15];
  const float* pse_b2 = (const float*)d_in[16];
  const float* pw1 = (const float*)d_in[17];
  const float* pb1 = (const float*)d_in[18];
  const float* pw2 = (const float*)d_in[19];
  const float* pb2 = (const float*)d_in[20];
  const float* vf_w1 = (const float*)d_in[21];
  const float* vf_b1 = (const float*)d_in[22];
  const float* vf_w2 = (const float*)d_in[23];
  const float* vf_b2 = (const float*)d_in[24];
  (void)in_sizes; (void)n_in; (void)out_size; (void)ws_size;

  char* base = (char*)d_ws;
  size_t off = 0;
  auto alloc = [&](size_t bytes) -> char* {
    char* p = base + off;
    off += (bytes + 255) & ~(size_t)255;
    return p;
  };
  unsigned short* fbf     = (unsigned short*)alloc((size_t)NB * 640 * 2);
  unsigned short* bufA    = (unsigned short*)alloc((size_t)NB * 1024 * 2);  // s1 / p1 / v1
  unsigned short* g1      = (unsigned short*)alloc((size_t)NB * 512 * 2);
  unsigned short* gate_in = (unsigned short*)alloc((size_t)NB * 512 * 2);
  unsigned short* gate_h  = (unsigned short*)alloc((size_t)NB * 256 * 2);
  unsigned short* prim    = (unsigned short*)alloc((size_t)NB * 256 * 2);
  float* wgt              = (float*)alloc((size_t)NB * 16 * 4);
  unsigned short* se_w1t  = (unsigned short*)alloc(512 * 512 * 2);
  unsigned short* se_w2t  = (unsigned short*)alloc(256 * 512 * 2);
  unsigned short* ge_w1t  = (unsigned short*)alloc(512 * 128 * 2);
  unsigned short* ge_w2t  = (unsigned short*)alloc(256 * 512 * 2);
  unsigned short* gt_w1t  = (unsigned short*)alloc(256 * 512 * 2);
  unsigned short* pse_w1t = (unsigned short*)alloc(512 * 512 * 2);
  unsigned short* pse_w2t = (unsigned short*)alloc(256 * 512 * 2);
  unsigned short* pw1t    = (unsigned short*)alloc((size_t)16 * 256 * 256 * 2);
  unsigned short* pw2t    = (unsigned short*)alloc((size_t)16 * 64 * 256 * 2);
  unsigned short* vf_w1t  = (unsigned short*)alloc(1024 * 640 * 2);
  unsigned short* vf_w2t  = (unsigned short*)alloc(512 * 1024 * 2);

  // outbuf [B][16][64] fp32 = 128MB, overlaid on bufA+g1+gate_in (dead by the
  // time prim_head_k runs; exactly 128MB contiguous).
  float* outbuf = (float*)bufA;

  float* mean_out = (float*)d_out;
  float* value_out = (float*)d_out + (size_t)NB * 32;

  fconv_k<<<dim3(10240), dim3(256), 0, stream>>>(features, fbf);

  TJobs jobs;
  auto setj = [&](int i, const float* s, unsigned short* d, int K, int N, int b) {
    jobs.src[i] = s; jobs.dst[i] = d; jobs.K[i] = K; jobs.N[i] = N; jobs.batch[i] = b;
  };
  setj(0, se_w1, se_w1t, 512, 512, 1);
  setj(1, se_w2, se_w2t, 512, 256, 1);
  setj(2, ge_w1, ge_w1t, 128, 512, 1);
  setj(3, ge_w2, ge_w2t, 512, 256, 1);
  setj(4, gt_w1, gt_w1t, 512, 256, 1);
  setj(5, pse_w1, pse_w1t, 512, 512, 1);
  setj(6, pse_w2, pse_w2t, 512, 256, 1);
  setj(7, pw1, pw1t, 256, 256, 16);
  setj(8, pw2, pw2t, 256, 64, 16);
  setj(9, vf_w1, vf_w1t, 640, 1024, 1);
  setj(10, vf_w2, vf_w2t, 1024, 512, 1);
  wtrans_k<<<dim3(1024, 11), dim3(256), 0, stream>>>(jobs);

  // s1 = relu(state @ se_w1 + b)
  gemm_k<true><<<dim3(256, 4), dim3(256), 0, stream>>>(fbf, 640, se_w1t, se_b1, bufA, 512, 512);
  // gate_in[:, :256] = relu(s1 @ se_w2 + b)
  gemm_k<true><<<dim3(256, 2), dim3(256), 0, stream>>>(bufA, 512, se_w2t, se_b2, gate_in, 512, 512);
  // g1 = relu(goal @ ge_w1 + b)
  gemm_k<true><<<dim3(256, 4), dim3(256), 0, stream>>>(fbf + 512, 640, ge_w1t, ge_b1, g1, 512, 128);
  // gate_in[:, 256:] = relu(g1 @ ge_w2 + b)
  gemm_k<true><<<dim3(256, 2), dim3(256), 0, stream>>>(g1, 512, ge_w2t, ge_b2, gate_in + 256, 512, 512);
  // gate_h = relu(gate_in @ gt_w1 + b)
  gemm_k<true><<<dim3(256, 2), dim3(256), 0, stream>>>(gate_in, 512, gt_w1t, gt_b1, gate_h, 256, 512);
  // weights = sigmoid(gate_h @ gt_w2 + b)
  gt2_k<<<dim3(2048), dim3(256), 0, stream>>>(gate_h, gt_w2, gt_b2, wgt);
  // p1 = relu(state @ pse_w1 + b)
  gemm_k<true><<<dim3(256, 4), dim3(256), 0, stream>>>(fbf, 640, pse_w1t, pse_b1, bufA, 512, 512);
  // prim = relu(p1 @ pse_w2 + b)
  gemm_k<true><<<dim3(256, 2), dim3(256), 0, stream>>>(bufA, 512, pse_w2t, pse_b2, prim, 256, 512);
  // v1 = relu(features @ vf_w1 + b)
  gemm_k<true><<<dim3(256, 8), dim3(256), 0, stream>>>(fbf, 640, vf_w1t, vf_b1, bufA, 1024, 640);
  // value = relu(v1 @ vf_w2 + b)  (fp32 out)
  gemm_k<false><<<dim3(256, 4), dim3(256), 0, stream>>>(bufA, 1024, vf_w2t, vf_b2, value_out, 512, 1024);
  // mean head: per-(rowtile,p) fused MLP, writes ivmu/iv (bufA region now dead -> outbuf)
  prim_head_k<<<dim3(256, 16), dim3(512), 0, stream>>>(prim, wgt, pw1t, pb1, pw2t, pb2, outbuf);
  // reduce over p
  mix_finish_k<<<dim3(1024), dim3(256), 0, stream>>>(outbuf, mean_out);
}

// Round 3
// 542.771 us; speedup vs baseline: 1.2359x; 1.1698x over previous
//
#include <hip/hip_runtime.h>
#include <stdint.h>

#define NB 32768

typedef __bf16 bf16x8 __attribute__((ext_vector_type(8)));
typedef float f32x4 __attribute__((ext_vector_type(4)));

__device__ __forceinline__ unsigned short f2bf(float f) {
  union { float f; unsigned u; } v; v.f = f;
  unsigned r = v.u + 0x7fffu + ((v.u >> 16) & 1u);
  return (unsigned short)(r >> 16);
}
__device__ __forceinline__ float bf2f(unsigned short h) {
  union { unsigned u; float f; } v; v.u = ((unsigned)h) << 16;
  return v.f;
}

// global -> LDS direct copy, 16B per lane. LDS dest is wave-uniform base + lane*16.
__device__ __forceinline__ void gld_lds16(void* lds, const void* g) {
  __builtin_amdgcn_global_load_lds(
      (__attribute__((address_space(1))) unsigned int*)(uintptr_t)g,
      (__attribute__((address_space(3))) unsigned int*)(uintptr_t)lds,
      16, 0, 0);
}

// ---------------- prep kernels ----------------

__global__ __launch_bounds__(256) void fconv_k(const float* __restrict__ src,
                                               unsigned short* __restrict__ dst) {
  size_t idx = ((size_t)blockIdx.x * 256 + threadIdx.x) * 8;
  float4 a = *(const float4*)(src + idx);
  float4 b = *(const float4*)(src + idx + 4);
  union { unsigned short us[8]; uint4 v; } u;
  u.us[0] = f2bf(a.x); u.us[1] = f2bf(a.y); u.us[2] = f2bf(a.z); u.us[3] = f2bf(a.w);
  u.us[4] = f2bf(b.x); u.us[5] = f2bf(b.y); u.us[6] = f2bf(b.z); u.us[7] = f2bf(b.w);
  *(uint4*)(dst + idx) = u.v;
}

struct TJobs {
  const float* src[11];
  unsigned short* dst[11];
  int K[11], N[11], batch[11];
};

// transpose fp32 [K][N] -> bf16 [N][K], batched, 32x32 tiles
__global__ __launch_bounds__(256) void wtrans_k(TJobs jobs) {
  const int job = blockIdx.y;
  const int K = jobs.K[job], N = jobs.N[job];
  const int KT = K >> 5, NT = N >> 5;
  const int ntiles = jobs.batch[job] * KT * NT;
  const int t = blockIdx.x;
  if (t >= ntiles) return;
  const int b = t / (KT * NT);
  const int rem = t - b * KT * NT;
  const int kt = rem / NT, nt = rem - kt * NT;
  const float* src = jobs.src[job] + (size_t)b * K * N;
  unsigned short* dst = jobs.dst[job] + (size_t)b * K * N;
  __shared__ float tile[32][33];
  const int i = threadIdx.x >> 5, jj = threadIdx.x & 31;
#pragma unroll
  for (int s = 0; s < 4; ++s)
    tile[i + 8 * s][jj] = src[(size_t)(kt * 32 + i + 8 * s) * N + nt * 32 + jj];
  __syncthreads();
#pragma unroll
  for (int s = 0; s < 4; ++s)
    dst[(size_t)(nt * 32 + i + 8 * s) * K + kt * 32 + jj] = f2bf(tile[jj][i + 8 * s]);
}

// ---------------- main GEMM: C = relu(A @ W + b), A bf16 [M][lda], WT bf16 [N][K] ----------------
// 128x128 tile, 4 waves (2x2), each wave 64x64 = 4x4 frags of 16x16x32.

template <bool OUT_BF16>
__global__ __launch_bounds__(256) void gemm_k(const unsigned short* __restrict__ A, int lda,
                                              const unsigned short* __restrict__ WT,
                                              const float* __restrict__ bias,
                                              void* __restrict__ Cout, int ldc, int K) {
  __shared__ unsigned short lds_a[128 * 32];
  __shared__ unsigned short lds_b[128 * 32];
  const int tid = threadIdx.x;
  const int l = tid & 63, w = tid >> 6;
  const int wm = w >> 1, wn = w & 1;
  const int lr = l & 15, lq = l >> 4;
  const int row0 = blockIdx.x << 7;
  const int col0 = blockIdx.y << 7;
  const int srow = tid >> 2;  // 0..63
  const int scg = tid & 3;
  const int wbase = tid & ~63;

  f32x4 acc[4][4] = {};

  for (int k0 = 0; k0 < K; k0 += 32) {
#pragma unroll
    for (int i = 0; i < 2; ++i) {
      const int r = i * 64 + srow;
      gld_lds16(&lds_a[(size_t)(i * 256 + wbase) * 8],
                A + (size_t)(row0 + r) * lda + k0 + scg * 8);
      gld_lds16(&lds_b[(size_t)(i * 256 + wbase) * 8],
                WT + (size_t)(col0 + r) * K + k0 + scg * 8);
    }
    __syncthreads();
    bf16x8 av[4], bv[4];
#pragma unroll
    for (int mf = 0; mf < 4; ++mf)
      av[mf] = *(const bf16x8*)&lds_a[((wm * 64 + mf * 16 + lr) << 5) + (lq << 3)];
#pragma unroll
    for (int nf = 0; nf < 4; ++nf)
      bv[nf] = *(const bf16x8*)&lds_b[((wn * 64 + nf * 16 + lr) << 5) + (lq << 3)];
#pragma unroll
    for (int mf = 0; mf < 4; ++mf)
#pragma unroll
      for (int nf = 0; nf < 4; ++nf)
        acc[mf][nf] = __builtin_amdgcn_mfma_f32_16x16x32_bf16(av[mf], bv[nf], acc[mf][nf], 0, 0, 0);
    __syncthreads();
  }

#pragma unroll
  for (int nf = 0; nf < 4; ++nf) {
    const int gc = col0 + wn * 64 + nf * 16 + lr;
    const float bb = bias[gc];
#pragma unroll
    for (int mf = 0; mf < 4; ++mf) {
      const int gr = row0 + wm * 64 + mf * 16 + (lq << 2);
#pragma unroll
      for (int r = 0; r < 4; ++r) {
        float v = acc[mf][nf][r] + bb;
        v = fmaxf(v, 0.0f);
        if (OUT_BF16)
          ((unsigned short*)Cout)[(size_t)(gr + r) * ldc + gc] = f2bf(v);
        else
          ((float*)Cout)[(size_t)(gr + r) * ldc + gc] = v;
      }
    }
  }
}

// ---------------- gate head 2: weights = sigmoid(gate_h @ gt_w2 + gt_b2), N=16 ----------------

__global__ __launch_bounds__(256) void gt2_k(const unsigned short* __restrict__ gate_h,
                                             const float* __restrict__ w2,
                                             const float* __restrict__ b2,
                                             float* __restrict__ wgt) {
  __shared__ float w_s[256 * 16];
  __shared__ unsigned short a_s[16 * 264];
  const int tid = threadIdx.x;
  const int row0 = blockIdx.x * 16;
  for (int i = tid; i < 256 * 16; i += 256) w_s[i] = w2[i];
  for (int i = tid; i < 512; i += 256) {
    const int r = i >> 5, cg = i & 31;
    *(uint4*)&a_s[r * 264 + cg * 8] =
        *(const uint4*)(gate_h + (size_t)(row0 + r) * 256 + cg * 8);
  }
  __syncthreads();
  const int rr = tid >> 4, col = tid & 15;
  float sum = b2[col];
#pragma unroll 8
  for (int k = 0; k < 256; ++k)
    sum += bf2f(a_s[rr * 264 + k]) * w_s[k * 16 + col];
  wgt[(size_t)(row0 + rr) * 16 + col] = 1.0f / (1.0f + __expf(-sum));
}

// ---------------- primitive head: per (row-tile, p) block ----------------
// block = 128 rows x one p, 8 waves (2 wm x 4 wn).
// All LDS staging is COALESCED row-major [row][k] with XOR chunk swizzle:
// LDS[r][kc] = G[r][kc ^ (r&mask)]; fragment reads use chunk lq ^ (r&mask).
// phase 1: h[128][256] = relu(prim_tile @ pw1[p] + pb1[p])  (h in LDS, K-tiled)
// phase 2: out[128][64] = h @ pw2[p] + pb2[p]               (pw2[p] LDS-staged once)
// epilogue: iv = wgt[row][p]*exp(-ls); write ivmu & iv fp32 to outbuf[row][p][64].

__global__ __launch_bounds__(512) void prim_head_k(
    const unsigned short* __restrict__ prim,   // [B][256] bf16
    const float* __restrict__ wgt,             // [B][16]
    const unsigned short* __restrict__ pw1t,   // [16][256n][256k] bf16
    const float* __restrict__ pb1,             // [16][256]
    const unsigned short* __restrict__ pw2t,   // [16][64n][256k] bf16
    const float* __restrict__ pb2,             // [16][64]
    float* __restrict__ outbuf)                // [B][16][64] fp32
{
  __shared__ unsigned short prim_s[128 * 32];   // 8KB  [row128][k32], 16B-chunk swizzle by row&3
  __shared__ unsigned short w1_s[256 * 32];     // 16KB [n256][k32],  16B-chunk swizzle by n&3
  __shared__ unsigned short h_s[32 * 128 * 8];  // 64KB [kq32][row128][8]
  __shared__ unsigned short pw2_s[64 * 256];    // 32KB [n64][k256],  16B-chunk swizzle by n&7
  __shared__ float out_s[128 * 64];             // 32KB
  const int tid = threadIdx.x;
  const int l = tid & 63;
  const int w = tid >> 6;
  const int lr = l & 15, lq = l >> 4;
  const int wm = w >> 2, wn = w & 3;   // wm 0..1, wn 0..3
  const int row0 = blockIdx.x << 7;
  const int p = blockIdx.y;
  const int wbase = tid & ~63;

  const unsigned short* w1p = pw1t + (size_t)p * 65536;
  const unsigned short* w2p = pw2t + (size_t)p * 16384;

  // stage pw2[p] (32KB): 2048 chunks; 32 consecutive lanes cover one 512B row.
  // LDS[n][kq] = G[n][kq ^ (n&7)]
#pragma unroll
  for (int i = 0; i < 4; ++i) {
    const int c = i * 512 + tid;
    const int n = c >> 5, kq = c & 31;
    const int kqs = kq ^ (n & 7);
    gld_lds16(&pw2_s[(size_t)(i * 512 + wbase) * 8], w2p + (size_t)n * 256 + kqs * 8);
  }

  // ---- phase 1: h = relu(prim @ pw1[p] + pb1[p]) ----
  f32x4 acc[4][4] = {};
  for (int ks = 0; ks < 8; ++ks) {
    const int k0 = ks * 32;
    {  // prim tile [row128][k32]: 512 chunks, 4 lanes per row (64B coalesced)
      const int rw = tid >> 2, kc = tid & 3;
      const int kcs = kc ^ (rw & 3);
      gld_lds16(&prim_s[(size_t)wbase * 8], prim + (size_t)(row0 + rw) * 256 + k0 + kcs * 8);
    }
#pragma unroll
    for (int i = 0; i < 2; ++i) {  // w1 tile [n256][k32]: 1024 chunks
      const int c = i * 512 + tid;
      const int n = c >> 2, kc = c & 3;
      const int kcs = kc ^ (n & 3);
      gld_lds16(&w1_s[(size_t)(i * 512 + wbase) * 8], w1p + (size_t)n * 256 + k0 + kcs * 8);
    }
    __syncthreads();
    bf16x8 av[4], bv[4];
#pragma unroll
    for (int mf = 0; mf < 4; ++mf) {
      const int r = wm * 64 + mf * 16 + lr;
      av[mf] = *(const bf16x8*)&prim_s[r * 32 + ((lq ^ (r & 3)) << 3)];
    }
#pragma unroll
    for (int nf = 0; nf < 4; ++nf) {
      const int n = wn * 64 + nf * 16 + lr;
      bv[nf] = *(const bf16x8*)&w1_s[n * 32 + ((lq ^ (n & 3)) << 3)];
    }
#pragma unroll
    for (int mf = 0; mf < 4; ++mf)
#pragma unroll
      for (int nf = 0; nf < 4; ++nf)
        acc[mf][nf] = __builtin_amdgcn_mfma_f32_16x16x32_bf16(av[mf], bv[nf], acc[mf][nf], 0, 0, 0);
    __syncthreads();
  }

  // write h (K-tiled layout [n>>3][row][n&7])
#pragma unroll
  for (int nf = 0; nf < 4; ++nf) {
    const int n = wn * 64 + nf * 16 + lr;
    const float bb = pb1[p * 256 + n];
#pragma unroll
    for (int mf = 0; mf < 4; ++mf) {
#pragma unroll
      for (int r = 0; r < 4; ++r) {
        const int rw = wm * 64 + mf * 16 + (lq << 2) + r;
        h_s[(size_t)((n >> 3) * 128 + rw) * 8 + (n & 7)] = f2bf(fmaxf(acc[mf][nf][r] + bb, 0.0f));
      }
    }
  }
  __syncthreads();

  // ---- phase 2: out = h @ pw2[p] + pb2[p] ----
  f32x4 acc2[4] = {};
#pragma unroll
  for (int kc = 0; kc < 8; ++kc) {
    const int n2 = wn * 16 + lr;
    const int g = kc * 4 + lq;                 // global 16B k-chunk index (0..31)
    const bf16x8 bv2 = *(const bf16x8*)&pw2_s[n2 * 256 + ((g ^ (n2 & 7)) << 3)];
#pragma unroll
    for (int mf = 0; mf < 4; ++mf) {
      const bf16x8 av2 =
          *(const bf16x8*)&h_s[((size_t)(kc * 4 + lq) * 128 + wm * 64 + mf * 16 + lr) * 8];
      acc2[mf] = __builtin_amdgcn_mfma_f32_16x16x32_bf16(av2, bv2, acc2[mf], 0, 0, 0);
    }
  }
  {
    const int d = wn * 16 + lr;
    const float bb = pb2[p * 64 + d];
#pragma unroll
    for (int mf = 0; mf < 4; ++mf)
#pragma unroll
      for (int r = 0; r < 4; ++r)
        out_s[(size_t)(wm * 64 + mf * 16 + (lq << 2) + r) * 64 + d] = acc2[mf][r] + bb;
  }
  __syncthreads();

  // ---- epilogue: iv = wgt*exp(-ls); write ivmu, iv ----
  {
    const int frow = tid >> 2;          // 0..127
    const int a0 = (tid & 3) * 8;       // 0,8,16,24
    const float wp = wgt[(size_t)(row0 + frow) * 16 + p];
    float* ob = outbuf + ((size_t)(row0 + frow) * 16 + p) * 64;
    float4 mu0 = *(float4*)&out_s[frow * 64 + a0];
    float4 mu1 = *(float4*)&out_s[frow * 64 + a0 + 4];
    float4 ls0 = *(float4*)&out_s[frow * 64 + 32 + a0];
    float4 ls1 = *(float4*)&out_s[frow * 64 + 32 + a0 + 4];
    float4 iv0, iv1, nm0, nm1;
    iv0.x = wp * __expf(-ls0.x); iv0.y = wp * __expf(-ls0.y);
    iv0.z = wp * __expf(-ls0.z); iv0.w = wp * __expf(-ls0.w);
    iv1.x = wp * __expf(-ls1.x); iv1.y = wp * __expf(-ls1.y);
    iv1.z = wp * __expf(-ls1.z); iv1.w = wp * __expf(-ls1.w);
    nm0.x = iv0.x * mu0.x; nm0.y = iv0.y * mu0.y; nm0.z = iv0.z * mu0.z; nm0.w = iv0.w * mu0.w;
    nm1.x = iv1.x * mu1.x; nm1.y = iv1.y * mu1.y; nm1.z = iv1.z * mu1.z; nm1.w = iv1.w * mu1.w;
    *(float4*)(ob + a0) = nm0;
    *(float4*)(ob + a0 + 4) = nm1;
    *(float4*)(ob + 32 + a0) = iv0;
    *(float4*)(ob + 32 + a0 + 4) = iv1;
  }
}

// ---------------- mixture finish: mean = sum_p ivmu / sum_p iv ----------------

__global__ __launch_bounds__(256) void mix_finish_k(const float* __restrict__ buf,  // [B][16][64]
                                                    float* __restrict__ mean_out) { // [B][32]
  const int gid = blockIdx.x * 256 + threadIdx.x;
  const int row = gid >> 3;
  const int a0 = (gid & 7) * 4;
  const float* rp = buf + (size_t)row * 1024;
  float nx = 0, ny = 0, nz = 0, nw = 0, dx = 0, dy = 0, dz = 0, dw = 0;
#pragma unroll
  for (int p = 0; p < 16; ++p) {
    float4 m = *(const float4*)(rp + p * 64 + a0);
    float4 v = *(const float4*)(rp + p * 64 + 32 + a0);
    nx += m.x; ny += m.y; nz += m.z; nw += m.w;
    dx += v.x; dy += v.y; dz += v.z; dw += v.w;
  }
  float4 res;
  res.x = nx / dx; res.y = ny / dy; res.z = nz / dz; res.w = nw / dw;
  *(float4*)(mean_out + (size_t)row * 32 + a0) = res;
}

// ---------------- launcher ----------------

extern "C" void kernel_launch(void* const* d_in, const int* in_sizes, int n_in,
                              void* d_out, int out_size, void* d_ws, size_t ws_size,
                              hipStream_t stream) {
  const float* features = (const float*)d_in[0];
  const float* se_w1 = (const float*)d_in[1];
  const float* se_b1 = (const float*)d_in[2];
  const float* se_w2 = (const float*)d_in[3];
  const float* se_b2 = (const float*)d_in[4];
  const float* ge_w1 = (const float*)d_in[5];
  const float* ge_b1 = (const float*)d_in[6];
  const float* ge_w2 = (const float*)d_in[7];
  const float* ge_b2 = (const float*)d_in[8];
  const float* gt_w1 = (const float*)d_in[9];
  const float* gt_b1 = (const float*)d_in[10];
  const float* gt_w2 = (const float*)d_in[11];
  const float* gt_b2 = (const float*)d_in[12];
  const float* pse_w1 = (const float*)d_in[13];
  const float* pse_b1 = (const float*)d_in[14];
  const float* pse_w2 = (const float*)d_in[15];
  const float* pse_b2 = (const float*)d_in[16];
  const float* pw1 = (const float*)d_in[17];
  const float* pb1 = (const float*)d_in[18];
  const float* pw2 = (const float*)d_in[19];
  const float* pb2 = (const float*)d_in[20];
  const float* vf_w1 = (const float*)d_in[21];
  const float* vf_b1 = (const float*)d_in[22];
  const float* vf_w2 = (const float*)d_in[23];
  const float* vf_b2 = (const float*)d_in[24];
  (void)in_sizes; (void)n_in; (void)out_size; (void)ws_size;

  char* base = (char*)d_ws;
  size_t off = 0;
  auto alloc = [&](size_t bytes) -> char* {
    char* p = base + off;
    off += (bytes + 255) & ~(size_t)255;
    return p;
  };
  unsigned short* fbf     = (unsigned short*)alloc((size_t)NB * 640 * 2);
  unsigned short* bufA    = (unsigned short*)alloc((size_t)NB * 1024 * 2);  // s1 / p1 / v1
  unsigned short* g1      = (unsigned short*)alloc((size_t)NB * 512 * 2);
  unsigned short* gate_in = (unsigned short*)alloc((size_t)NB * 512 * 2);
  unsigned short* gate_h  = (unsigned short*)alloc((size_t)NB * 256 * 2);
  unsigned short* prim    = (unsigned short*)alloc((size_t)NB * 256 * 2);
  float* wgt              = (float*)alloc((size_t)NB * 16 * 4);
  unsigned short* se_w1t  = (unsigned short*)alloc(512 * 512 * 2);
  unsigned short* se_w2t  = (unsigned short*)alloc(256 * 512 * 2);
  unsigned short* ge_w1t  = (unsigned short*)alloc(512 * 128 * 2);
  unsigned short* ge_w2t  = (unsigned short*)alloc(256 * 512 * 2);
  unsigned short* gt_w1t  = (unsigned short*)alloc(256 * 512 * 2);
  unsigned short* pse_w1t = (unsigned short*)alloc(512 * 512 * 2);
  unsigned short* pse_w2t = (unsigned short*)alloc(256 * 512 * 2);
  unsigned short* pw1t    = (unsigned short*)alloc((size_t)16 * 256 * 256 * 2);
  unsigned short* pw2t    = (unsigned short*)alloc((size_t)16 * 64 * 256 * 2);
  unsigned short* vf_w1t  = (unsigned short*)alloc(1024 * 640 * 2);
  unsigned short* vf_w2t  = (unsigned short*)alloc(512 * 1024 * 2);

  // outbuf [B][16][64] fp32 = 128MB, overlaid on bufA+g1+gate_in (dead by the
  // time prim_head_k runs; exactly 128MB contiguous).
  float* outbuf = (float*)bufA;

  float* mean_out = (float*)d_out;
  float* value_out = (float*)d_out + (size_t)NB * 32;

  fconv_k<<<dim3(10240), dim3(256), 0, stream>>>(features, fbf);

  TJobs jobs;
  auto setj = [&](int i, const float* s, unsigned short* d, int K, int N, int b) {
    jobs.src[i] = s; jobs.dst[i] = d; jobs.K[i] = K; jobs.N[i] = N; jobs.batch[i] = b;
  };
  setj(0, se_w1, se_w1t, 512, 512, 1);
  setj(1, se_w2, se_w2t, 512, 256, 1);
  setj(2, ge_w1, ge_w1t, 128, 512, 1);
  setj(3, ge_w2, ge_w2t, 512, 256, 1);
  setj(4, gt_w1, gt_w1t, 512, 256, 1);
  setj(5, pse_w1, pse_w1t, 512, 512, 1);
  setj(6, pse_w2, pse_w2t, 512, 256, 1);
  setj(7, pw1, pw1t, 256, 256, 16);
  setj(8, pw2, pw2t, 256, 64, 16);
  setj(9, vf_w1, vf_w1t, 640, 1024, 1);
  setj(10, vf_w2, vf_w2t, 1024, 512, 1);
  wtrans_k<<<dim3(1024, 11), dim3(256), 0, stream>>>(jobs);

  // s1 = relu(state @ se_w1 + b)
  gemm_k<true><<<dim3(256, 4), dim3(256), 0, stream>>>(fbf, 640, se_w1t, se_b1, bufA, 512, 512);
  // gate_in[:, :256] = relu(s1 @ se_w2 + b)
  gemm_k<true><<<dim3(256, 2), dim3(256), 0, stream>>>(bufA, 512, se_w2t, se_b2, gate_in, 512, 512);
  // g1 = relu(goal @ ge_w1 + b)
  gemm_k<true><<<dim3(256, 4), dim3(256), 0, stream>>>(fbf + 512, 640, ge_w1t, ge_b1, g1, 512, 128);
  // gate_in[:, 256:] = relu(g1 @ ge_w2 + b)
  gemm_k<true><<<dim3(256, 2), dim3(256), 0, stream>>>(g1, 512, ge_w2t, ge_b2, gate_in + 256, 512, 512);
  // gate_h = relu(gate_in @ gt_w1 + b)
  gemm_k<true><<<dim3(256, 2), dim3(256), 0, stream>>>(gate_in, 512, gt_w1t, gt_b1, gate_h, 256, 512);
  // weights = sigmoid(gate_h @ gt_w2 + b)
  gt2_k<<<dim3(2048), dim3(256), 0, stream>>>(gate_h, gt_w2, gt_b2, wgt);
  // p1 = relu(state @ pse_w1 + b)
  gemm_k<true><<<dim3(256, 4), dim3(256), 0, stream>>>(fbf, 640, pse_w1t, pse_b1, bufA, 512, 512);
  // prim = relu(p1 @ pse_w2 + b)
  gemm_k<true><<<dim3(256, 2), dim3(256), 0, stream>>>(bufA, 512, pse_w2t, pse_b2, prim, 256, 512);
  // v1 = relu(features @ vf_w1 + b)
  gemm_k<true><<<dim3(256, 8), dim3(256), 0, stream>>>(fbf, 640, vf_w1t, vf_b1, bufA, 1024, 640);
  // value = relu(v1 @ vf_w2 + b)  (fp32 out)
  gemm_k<false><<<dim3(256, 4), dim3(256), 0, stream>>>(bufA, 1024, vf_w2t, vf_b2, value_out, 512, 1024);
  // mean head: per-(rowtile,p) fused MLP, writes ivmu/iv (bufA region now dead -> outbuf)
  prim_head_k<<<dim3(256, 16), dim3(512), 0, stream>>>(prim, wgt, pw1t, pb1, pw2t, pb2, outbuf);
  // reduce over p
  mix_finish_k<<<dim3(1024), dim3(256), 0, stream>>>(outbuf, mean_out);
}